// Round 5
// baseline (143.812 us; speedup 1.0000x reference)
//
#include <hip/hip_runtime.h>
#include <math.h>

// ---------------- kernel 1: exclusive scan of counts -> starts -----------------
__global__ void scan_kernel(const int* __restrict__ counts,
                            int* __restrict__ starts, int E) {
    __shared__ int lds[1024];
    int tid = threadIdx.x;
    int base = tid * 4;
    int c0 = (base + 0 < E) ? counts[base + 0] : 0;
    int c1 = (base + 1 < E) ? counts[base + 1] : 0;
    int c2 = (base + 2 < E) ? counts[base + 2] : 0;
    int c3 = (base + 3 < E) ? counts[base + 3] : 0;
    lds[tid] = c0 + c1 + c2 + c3;
    __syncthreads();
    for (int off = 1; off < 1024; off <<= 1) {
        int v = lds[tid];
        int a = (tid >= off) ? lds[tid - off] : 0;
        __syncthreads();
        lds[tid] = v + a;
        __syncthreads();
    }
    int excl = (tid > 0) ? lds[tid - 1] : 0;
    if (base + 0 < E) starts[base + 0] = excl; excl += c0;
    if (base + 1 < E) starts[base + 1] = excl; excl += c1;
    if (base + 2 < E) starts[base + 2] = excl; excl += c2;
    if (base + 3 < E) starts[base + 3] = excl;
}

__device__ __forceinline__ float4 qmul4(float4 a, float4 b) {
    return make_float4(
        a.w*b.x + a.x*b.w + a.y*b.z - a.z*b.y,
        a.w*b.y - a.x*b.z + a.y*b.w + a.z*b.x,
        a.w*b.z + a.x*b.y - a.y*b.x + a.z*b.w,
        a.w*b.w - a.x*b.x - a.y*b.y - a.z*b.z);
}

// rotate v=(0,1,0) by q_inv(q) = (-x,-y,-z,w), reference q_rot formula
__device__ __forceinline__ void qinv_rot_up(float4 q, float out[3]) {
    float qx = -q.x, qy = -q.y, qz = -q.z, qw = q.w;
    float tx = -2.f*qz;
    float ty = 0.f;
    float tz = 2.f*qx;
    out[0] = 0.f + qw*tx + (qy*tz - qz*ty);
    out[1] = 1.f + qw*ty + (qz*tx - qx*tz);
    out[2] = 0.f + qw*tz + (qx*ty - qy*tx);
}

__device__ __forceinline__ float wave_sum(float v) {
    v += __shfl_xor(v, 32);
    v += __shfl_xor(v, 16);
    v += __shfl_xor(v, 8);
    v += __shfl_xor(v, 4);
    v += __shfl_xor(v, 2);
    v += __shfl_xor(v, 1);
    return v;
}

__device__ void jacobi3f(float A[3][3], float V[3][3]) {
    V[0][0]=1.f; V[0][1]=0.f; V[0][2]=0.f;
    V[1][0]=0.f; V[1][1]=1.f; V[1][2]=0.f;
    V[2][0]=0.f; V[2][1]=0.f; V[2][2]=1.f;
    for (int sweep = 0; sweep < 6; ++sweep) {
        float off = A[0][1]*A[0][1] + A[0][2]*A[0][2] + A[1][2]*A[1][2];
        float dia = A[0][0]*A[0][0] + A[1][1]*A[1][1] + A[2][2]*A[2][2];
        if (off <= 1e-12f * (dia + 1e-30f)) break;
        for (int p = 0; p < 2; ++p) for (int q = p + 1; q < 3; ++q) {
            float apq = A[p][q];
            if (fabsf(apq) < 1e-30f) continue;
            float theta = (A[q][q] - A[p][p]) / (2.0f * apq);
            float t = ((theta >= 0.f) ? 1.f : -1.f) / (fabsf(theta) + sqrtf(theta*theta + 1.f));
            float cc = 1.f / sqrtf(t*t + 1.f);
            float ss = t * cc;
            float app = A[p][p], aqq = A[q][q];
            A[p][p] = app - t * apq;
            A[q][q] = aqq + t * apq;
            A[p][q] = 0.f; A[q][p] = 0.f;
            int r = 3 - p - q;
            float arp = A[r][p], arq = A[r][q];
            A[r][p] = cc*arp - ss*arq; A[p][r] = A[r][p];
            A[r][q] = ss*arp + cc*arq; A[q][r] = A[r][q];
            for (int i = 0; i < 3; ++i) {
                float vip = V[i][p], viq = V[i][q];
                V[i][p] = cc*vip - ss*viq;
                V[i][q] = ss*vip + cc*viq;
            }
        }
    }
}

__device__ void mat2quatf(const float R[3][3], float q[4]) {
    const float eps = 1e-12f;
    float tr = R[0][0] + R[1][1] + R[2][2];
    if (tr > 0.f) {
        float S = sqrtf(fmaxf(tr + 1.f, eps)) * 2.f;
        q[0] = (R[2][1]-R[1][2])/S; q[1] = (R[0][2]-R[2][0])/S;
        q[2] = (R[1][0]-R[0][1])/S; q[3] = 0.25f*S;
    } else if ((R[0][0] > R[1][1]) && (R[0][0] > R[2][2])) {
        float S = sqrtf(fmaxf(1.f + R[0][0] - R[1][1] - R[2][2], eps)) * 2.f;
        q[0] = 0.25f*S; q[1] = (R[0][1]+R[1][0])/S;
        q[2] = (R[0][2]+R[2][0])/S; q[3] = (R[2][1]-R[1][2])/S;
    } else if (R[1][1] > R[2][2]) {
        float S = sqrtf(fmaxf(1.f + R[1][1] - R[0][0] - R[2][2], eps)) * 2.f;
        q[0] = (R[0][1]+R[1][0])/S; q[1] = 0.25f*S;
        q[2] = (R[1][2]+R[2][1])/S; q[3] = (R[0][2]-R[2][0])/S;
    } else {
        float S = sqrtf(fmaxf(1.f + R[2][2] - R[0][0] - R[1][1], eps)) * 2.f;
        q[0] = (R[0][2]+R[2][0])/S; q[1] = (R[1][2]+R[2][1])/S;
        q[2] = 0.25f*S; q[3] = (R[1][0]-R[0][1])/S;
    }
}

// ---------------- kernel 2: fused per-segment stats + solve --------------------
// One 256-thread block (4 waves) per segment: all waves stream the same
// segment (zero intra-block imbalance, block time = ceil(c/256) iters),
// one LDS stage combines the 4 wave-sums, wave 0 does the 3x3 solve and
// stores 5 per-segment losses (no atomics).
#define NS 29
__global__ __launch_bounds__(256) void fused_kernel(
    const float* __restrict__ pred_t, const float4* __restrict__ pred_q,
    const float* __restrict__ gt_t,   const float4* __restrict__ gt_q,
    const int* __restrict__ counts, const int* __restrict__ starts,
    float* __restrict__ segloss, int E)
{
    int e = blockIdx.x;
    int tid = threadIdx.x;
    int lane = tid & 63;
    int wv = tid >> 6;
    int start = starts[e];
    int ci = counts[e];
    float4 q0p = pred_q[start];
    float4 q0g = gt_q[start];
    float4 q0pi = make_float4(-q0p.x, -q0p.y, -q0p.z, q0p.w);
    float4 q0gi = make_float4(-q0g.x, -q0g.y, -q0g.z, q0g.w);
    float t0x = pred_t[3*start+0], t0y = pred_t[3*start+1], t0z = pred_t[3*start+2];
    bool small_c = (ci < 4);

    // acc: 0-2 sum_p, 3-5 sum_g, 6 sum|p|^2, 7 sum|g|^2, 8-16 H_raw,
    // 17-26 M upper tri, 27 sum(1-cos_grav), 28 sum(1-dot_deg^2) [ci<4 only]
    float acc[NS];
    #pragma unroll
    for (int k = 0; k < NS; ++k) acc[k] = 0.f;

    for (int i = tid; i < ci; i += 256) {
        int n = start + i;
        float px = pred_t[3*n+0], py = pred_t[3*n+1], pz = pred_t[3*n+2];
        float gx = gt_t[3*n+0],  gy = gt_t[3*n+1],  gz = gt_t[3*n+2];
        float4 pq = pred_q[n];
        float4 gq = gt_q[n];

        acc[0] += px; acc[1] += py; acc[2] += pz;
        acc[3] += gx; acc[4] += gy; acc[5] += gz;
        acc[6] += px*px + py*py + pz*pz;
        acc[7] += gx*gx + gy*gy + gz*gz;
        acc[8]  += px*gx; acc[9]  += px*gy; acc[10] += px*gz;
        acc[11] += py*gx; acc[12] += py*gy; acc[13] += py*gz;
        acc[14] += pz*gx; acc[15] += pz*gy; acc[16] += pz*gz;

        // m_i = d(dot)/d(q_align_i) where dot = <q_mul(q_align, pq), gq>
        float mx =  pq.w*gq.x - pq.z*gq.y + pq.y*gq.z - pq.x*gq.w;
        float my =  pq.z*gq.x + pq.w*gq.y - pq.x*gq.z - pq.y*gq.w;
        float mz = -pq.y*gq.x + pq.x*gq.y + pq.w*gq.z - pq.z*gq.w;
        float mw =  pq.x*gq.x + pq.y*gq.y + pq.z*gq.z + pq.w*gq.w;
        acc[17] += mx*mx; acc[18] += mx*my; acc[19] += mx*mz; acc[20] += mx*mw;
        acc[21] += my*my; acc[22] += my*mz; acc[23] += my*mw;
        acc[24] += mz*mz; acc[25] += mz*mw; acc[26] += mw*mw;

        // gravity: pred_q/gt_q are unit quats -> |pu| = |gu| = 1 (to fp32 eps),
        // so the reference's norm/div is a no-op; use the raw dot.
        float pu[3], gu[3];
        qinv_rot_up(pq, pu);
        qinv_rot_up(gq, gu);
        float cosv = pu[0]*gu[0] + pu[1]*gu[1] + pu[2]*gu[2];
        acc[27] += 1.f - cosv;

        if (small_c) {
            float4 aa = qmul4(q0pi, pq);
            float4 bb = qmul4(q0gi, gq);
            float dd = aa.x*bb.x + aa.y*bb.y + aa.z*bb.z + aa.w*bb.w;
            acc[28] += 1.f - dd*dd;
        }
    }

    #pragma unroll
    for (int k = 0; k < NS; ++k) acc[k] = wave_sum(acc[k]);

    __shared__ float red[4][NS];
    if (lane == 0) {
        #pragma unroll
        for (int k = 0; k < NS; ++k) red[wv][k] = acc[k];
    }
    __syncthreads();
    if (wv != 0) return;   // waves 1-3 done (after the barrier: legal)

    float A[NS];
    #pragma unroll
    for (int k = 0; k < NS; ++k)
        A[k] = red[0][k] + red[1][k] + red[2][k] + red[3][k];

    // ---- per-segment solve on wave 0 (wave-uniform, redundant across lanes) ----
    float c = (float)ci;
    float mu_p[3] = { A[0]/c, A[1]/c, A[2]/c };
    float mu_g[3] = { A[3]/c, A[4]/c, A[5]/c };
    float pp_c = A[6] - c*(mu_p[0]*mu_p[0]+mu_p[1]*mu_p[1]+mu_p[2]*mu_p[2]);
    float gg_c = A[7] - c*(mu_g[0]*mu_g[0]+mu_g[1]*mu_g[1]+mu_g[2]*mu_g[2]);
    float H[3][3];
    H[0][0]=A[8] -c*mu_p[0]*mu_g[0]; H[0][1]=A[9] -c*mu_p[0]*mu_g[1]; H[0][2]=A[10]-c*mu_p[0]*mu_g[2];
    H[1][0]=A[11]-c*mu_p[1]*mu_g[0]; H[1][1]=A[12]-c*mu_p[1]*mu_g[1]; H[1][2]=A[13]-c*mu_p[1]*mu_g[2];
    H[2][0]=A[14]-c*mu_p[2]*mu_g[0]; H[2][1]=A[15]-c*mu_p[2]*mu_g[1]; H[2][2]=A[16]-c*mu_p[2]*mu_g[2];
    float g_var = gg_c / (c - 1.0f);
    bool deg = small_c || (g_var < 1e-4f);
    float trans, rot, scale = 0.f;
    if (deg) {
        float s28;
        if (small_c) {
            s28 = A[28];
        } else {
            // data-degenerate large segment (essentially never): re-stream q
            float local = 0.f;
            for (int i = lane; i < ci; i += 64) {
                int n = start + i;
                float4 aa = qmul4(q0pi, pred_q[n]);
                float4 bb = qmul4(q0gi, gt_q[n]);
                float dd = aa.x*bb.x + aa.y*bb.y + aa.z*bb.z + aa.w*bb.w;
                local += 1.f - dd*dd;
            }
            s28 = wave_sum(local);
        }
        float trH = H[0][0] + H[1][1] + H[2][2];
        trans = (pp_c - 2.f*trH + gg_c) / (c * 3.f);
        rot = s28 / c;
    } else {
        float B[3][3], V[3][3];
        for (int i = 0; i < 3; ++i)
            for (int j = 0; j < 3; ++j)
                B[i][j] = H[0][i]*H[0][j] + H[1][i]*H[1][j] + H[2][i]*H[2][j];
        jacobi3f(B, V);
        float lam[3] = { B[0][0], B[1][1], B[2][2] };
        int idx[3] = {0, 1, 2};
        if (lam[idx[0]] < lam[idx[1]]) { int t = idx[0]; idx[0] = idx[1]; idx[1] = t; }
        if (lam[idx[0]] < lam[idx[2]]) { int t = idx[0]; idx[0] = idx[2]; idx[2] = t; }
        if (lam[idx[1]] < lam[idx[2]]) { int t = idx[1]; idx[1] = idx[2]; idx[2] = t; }
        float v1[3], v2[3], v3[3];
        for (int i = 0; i < 3; ++i) { v1[i] = V[i][idx[0]]; v2[i] = V[i][idx[1]]; v3[i] = V[i][idx[2]]; }
        float detV = v1[0]*(v2[1]*v3[2]-v2[2]*v3[1])
                   - v1[1]*(v2[0]*v3[2]-v2[2]*v3[0])
                   + v1[2]*(v2[0]*v3[1]-v2[1]*v3[0]);
        float sgnV = (detV < 0.f) ? -1.f : 1.f;
        float u1[3], u2[3], u3[3];
        for (int i = 0; i < 3; ++i) u1[i] = H[i][0]*v1[0] + H[i][1]*v1[1] + H[i][2]*v1[2];
        float n1 = fmaxf(sqrtf(u1[0]*u1[0]+u1[1]*u1[1]+u1[2]*u1[2]), 1e-30f);
        for (int i = 0; i < 3; ++i) u1[i] /= n1;
        for (int i = 0; i < 3; ++i) u2[i] = H[i][0]*v2[0] + H[i][1]*v2[1] + H[i][2]*v2[2];
        float d12 = u1[0]*u2[0]+u1[1]*u2[1]+u1[2]*u2[2];
        for (int i = 0; i < 3; ++i) u2[i] -= d12*u1[i];
        float n2 = fmaxf(sqrtf(u2[0]*u2[0]+u2[1]*u2[1]+u2[2]*u2[2]), 1e-30f);
        for (int i = 0; i < 3; ++i) u2[i] /= n2;
        u3[0] = u1[1]*u2[2] - u1[2]*u2[1];
        u3[1] = u1[2]*u2[0] - u1[0]*u2[2];
        u3[2] = u1[0]*u2[1] - u1[1]*u2[0];
        // R = v1 u1^T + v2 u2^T + sgnV * v3 u3^T  (== reference V diag(1,1,sgn) U^T)
        float R[3][3];
        for (int i = 0; i < 3; ++i)
            for (int k = 0; k < 3; ++k)
                R[i][k] = v1[i]*u1[k] + v2[i]*u2[k] + sgnV*v3[i]*u3[k];
        float nom = 0.f;
        for (int k = 0; k < 3; ++k)
            for (int j = 0; j < 3; ++j)
                nom += R[k][j] * H[j][k];
        float denom = pp_c;
        float s = 1.f;
        if (denom > 1e-6f) {
            s = nom / fmaxf(denom, 1e-6f);
            s = fminf(fmaxf(s, 1e-3f), 1e3f);
        }
        trans = (s*s*denom - 2.f*s*nom + gg_c) / (c * 3.f);
        float ls = logf(fabsf(s) + 1e-6f);
        scale = ls * ls;
        float q[4];
        mat2quatf(R, q);
        float quad = q[0]*q[0]*A[17] + q[1]*q[1]*A[21] + q[2]*q[2]*A[24] + q[3]*q[3]*A[26]
            + 2.f*(q[0]*q[1]*A[18] + q[0]*q[2]*A[19] + q[0]*q[3]*A[20]
                 + q[1]*q[2]*A[22] + q[1]*q[3]*A[23] + q[2]*q[3]*A[25]);
        rot = (c - quad) / c;
    }
    float grav = A[27] / c;
    float mag = sqrtf(t0x*t0x + t0y*t0y + t0z*t0z);
    float ml = fmaxf(mag - 15.f, 0.f);
    float leash = ml * ml;
    float myval = (lane == 0) ? trans
                : (lane == 1) ? rot
                : (lane == 2) ? grav
                : (lane == 3) ? leash : scale;
    if (lane < 5) segloss[lane * E + e] = myval;
}

// ---------------- kernel 3: reduce 5 x E segment losses -> out[5] --------------
__global__ __launch_bounds__(256) void reduce_kernel(
    const float* __restrict__ segloss, float* __restrict__ out, int E)
{
    int k = blockIdx.x;
    const float* src = segloss + (size_t)k * E;
    float local = 0.f;
    for (int i = threadIdx.x; i < E; i += 256) local = local + src[i];
    local = wave_sum(local);
    __shared__ float red[4];
    int lane = threadIdx.x & 63;
    int wv = threadIdx.x >> 6;
    if (lane == 0) red[wv] = local;
    __syncthreads();
    if (threadIdx.x == 0)
        out[k] = (red[0] + red[1] + red[2] + red[3]) / (float)E;
}

extern "C" void kernel_launch(void* const* d_in, const int* in_sizes, int n_in,
                              void* d_out, int out_size, void* d_ws, size_t ws_size,
                              hipStream_t stream) {
    const float*  pred_t = (const float*)d_in[0];
    const float4* pred_q = (const float4*)d_in[1];
    const float*  gt_t   = (const float*)d_in[2];
    const float4* gt_q   = (const float4*)d_in[3];
    const int*    counts = (const int*)d_in[4];
    int E = in_sizes[4];

    int* starts = (int*)d_ws;
    size_t off = ((size_t)E * sizeof(int) + 255) & ~(size_t)255;
    float* segloss = (float*)((char*)d_ws + off);

    scan_kernel<<<1, 1024, 0, stream>>>(counts, starts, E);
    fused_kernel<<<E, 256, 0, stream>>>(pred_t, pred_q, gt_t, gt_q,
                                        counts, starts, segloss, E);
    reduce_kernel<<<5, 256, 0, stream>>>(segloss, (float*)d_out, E);
}

// Round 6
// 118.507 us; speedup vs baseline: 1.2135x; 1.2135x over previous
//
#include <hip/hip_runtime.h>
#include <math.h>

// ---------------- kernel 1: exclusive scan of counts + zero d_out --------------
__global__ void scan_kernel(const int* __restrict__ counts,
                            int* __restrict__ starts,
                            float* __restrict__ out, int E) {
    __shared__ int lds[1024];
    int tid = threadIdx.x;
    if (tid < 5) out[tid] = 0.0f;
    int base = tid * 4;
    int c0 = (base + 0 < E) ? counts[base + 0] : 0;
    int c1 = (base + 1 < E) ? counts[base + 1] : 0;
    int c2 = (base + 2 < E) ? counts[base + 2] : 0;
    int c3 = (base + 3 < E) ? counts[base + 3] : 0;
    lds[tid] = c0 + c1 + c2 + c3;
    __syncthreads();
    for (int off = 1; off < 1024; off <<= 1) {
        int v = lds[tid];
        int a = (tid >= off) ? lds[tid - off] : 0;
        __syncthreads();
        lds[tid] = v + a;
        __syncthreads();
    }
    int excl = (tid > 0) ? lds[tid - 1] : 0;
    if (base + 0 < E) starts[base + 0] = excl; excl += c0;
    if (base + 1 < E) starts[base + 1] = excl; excl += c1;
    if (base + 2 < E) starts[base + 2] = excl; excl += c2;
    if (base + 3 < E) starts[base + 3] = excl;
}

__device__ __forceinline__ float4 qmul4(float4 a, float4 b) {
    return make_float4(
        a.w*b.x + a.x*b.w + a.y*b.z - a.z*b.y,
        a.w*b.y - a.x*b.z + a.y*b.w + a.z*b.x,
        a.w*b.z + a.x*b.y - a.y*b.x + a.z*b.w,
        a.w*b.w - a.x*b.x - a.y*b.y - a.z*b.z);
}

// rotate v=(0,1,0) by q_inv(q) = (-x,-y,-z,w), reference q_rot formula
__device__ __forceinline__ void qinv_rot_up(float4 q, float out[3]) {
    float qx = -q.x, qy = -q.y, qz = -q.z, qw = q.w;
    float tx = -2.f*qz;
    float ty = 0.f;
    float tz = 2.f*qx;
    out[0] = 0.f + qw*tx + (qy*tz - qz*ty);
    out[1] = 1.f + qw*ty + (qz*tx - qx*tz);
    out[2] = 0.f + qw*tz + (qx*ty - qy*tx);
}

__device__ __forceinline__ float wave_sum(float v) {
    v += __shfl_xor(v, 32);
    v += __shfl_xor(v, 16);
    v += __shfl_xor(v, 8);
    v += __shfl_xor(v, 4);
    v += __shfl_xor(v, 2);
    v += __shfl_xor(v, 1);
    return v;
}

// ---------------- kernel 2: per-segment sufficient statistics ------------------
// 4 independent waves per 256-block, one segment per wave, NO barrier.
// Software-pipelined: iteration j+1's 8 loads issue before iteration j's
// accumulation, doubling per-wave bytes in flight (latency-bound per R5 PMC).
// stats row (32 floats): 0-2 sum_p, 3-5 sum_g, 6 sum|p|^2, 7 sum|g|^2,
// 8-16 H_raw, 17-26 M upper tri, 27 sum(1-cos_grav), 28 sum(1-dot_deg^2) [ci<4]
#define NS 29
__global__ __launch_bounds__(256) void pass1_kernel(
    const float* __restrict__ pred_t, const float4* __restrict__ pred_q,
    const float* __restrict__ gt_t,   const float4* __restrict__ gt_q,
    const int* __restrict__ counts, const int* __restrict__ starts,
    float* __restrict__ segacc, int E)
{
    int wv = threadIdx.x >> 6;
    int lane = threadIdx.x & 63;
    int e = blockIdx.x * 4 + wv;
    if (e >= E) return;
    int start = starts[e];
    int ci = counts[e];
    bool small_c = (ci < 4);
    float4 q0p = pred_q[start];
    float4 q0g = gt_q[start];
    float4 q0pi = make_float4(-q0p.x, -q0p.y, -q0p.z, q0p.w);
    float4 q0gi = make_float4(-q0g.x, -q0g.y, -q0g.z, q0g.w);

    float acc[NS];
    #pragma unroll
    for (int k = 0; k < NS; ++k) acc[k] = 0.f;

    int iters = (ci + 63) >> 6;
    int i = lane;
    // prologue: load slot 0 (clamped index; counts >= 2 always)
    int m = start + min(i, ci - 1);
    float px = pred_t[3*m+0], py = pred_t[3*m+1], pz = pred_t[3*m+2];
    float gx = gt_t[3*m+0],  gy = gt_t[3*m+1],  gz = gt_t[3*m+2];
    float4 pq = pred_q[m];
    float4 gq = gt_q[m];

    for (int j = 0; ; ) {
        // ---- prefetch next slot before consuming current ----
        float npx = 0.f, npy = 0.f, npz = 0.f, ngx = 0.f, ngy = 0.f, ngz = 0.f;
        float4 npq = make_float4(0.f,0.f,0.f,0.f), ngq = npq;
        bool have_next = (j + 1 < iters);
        if (have_next) {
            int m2 = start + min(i + 64, ci - 1);
            npx = pred_t[3*m2+0]; npy = pred_t[3*m2+1]; npz = pred_t[3*m2+2];
            ngx = gt_t[3*m2+0];  ngy = gt_t[3*m2+1];  ngz = gt_t[3*m2+2];
            npq = pred_q[m2];
            ngq = gt_q[m2];
        }
        // ---- accumulate current (predicated on validity) ----
        if (i < ci) {
            acc[0] += px; acc[1] += py; acc[2] += pz;
            acc[3] += gx; acc[4] += gy; acc[5] += gz;
            acc[6] += px*px + py*py + pz*pz;
            acc[7] += gx*gx + gy*gy + gz*gz;
            acc[8]  += px*gx; acc[9]  += px*gy; acc[10] += px*gz;
            acc[11] += py*gx; acc[12] += py*gy; acc[13] += py*gz;
            acc[14] += pz*gx; acc[15] += pz*gy; acc[16] += pz*gz;

            // m_i = d(dot)/d(q_align_i), dot = <q_mul(q_align, pq), gq>
            float mx =  pq.w*gq.x - pq.z*gq.y + pq.y*gq.z - pq.x*gq.w;
            float my =  pq.z*gq.x + pq.w*gq.y - pq.x*gq.z - pq.y*gq.w;
            float mz = -pq.y*gq.x + pq.x*gq.y + pq.w*gq.z - pq.z*gq.w;
            float mw =  pq.x*gq.x + pq.y*gq.y + pq.z*gq.z + pq.w*gq.w;
            acc[17] += mx*mx; acc[18] += mx*my; acc[19] += mx*mz; acc[20] += mx*mw;
            acc[21] += my*my; acc[22] += my*mz; acc[23] += my*mw;
            acc[24] += mz*mz; acc[25] += mz*mw; acc[26] += mw*mw;

            // gravity: unit quats -> |pu|=|gu|=1, skip norm/div (R5-verified)
            float pu[3], gu[3];
            qinv_rot_up(pq, pu);
            qinv_rot_up(gq, gu);
            float cosv = pu[0]*gu[0] + pu[1]*gu[1] + pu[2]*gu[2];
            acc[27] += 1.f - cosv;

            if (small_c) {
                float4 aa = qmul4(q0pi, pq);
                float4 bb = qmul4(q0gi, gq);
                float dd = aa.x*bb.x + aa.y*bb.y + aa.z*bb.z + aa.w*bb.w;
                acc[28] += 1.f - dd*dd;
            }
        }
        if (!have_next) break;
        px = npx; py = npy; pz = npz;
        gx = ngx; gy = ngy; gz = ngz;
        pq = npq; gq = ngq;
        i += 64; ++j;
    }

    #pragma unroll
    for (int k = 0; k < NS; ++k) acc[k] = wave_sum(acc[k]);

    // lane k stores acc[k] -> one coalesced 116B store per segment
    float outv = 0.f;
    #pragma unroll
    for (int k = 0; k < NS; ++k)
        if (lane == k) outv = acc[k];
    if (lane < NS)
        segacc[(size_t)e*32 + lane] = outv;
}

// ---------------- kernel 3: per-LANE solve + loss reduction (fp32) -------------
__device__ void jacobi3f(float A[3][3], float V[3][3]) {
    V[0][0]=1.f; V[0][1]=0.f; V[0][2]=0.f;
    V[1][0]=0.f; V[1][1]=1.f; V[1][2]=0.f;
    V[2][0]=0.f; V[2][1]=0.f; V[2][2]=1.f;
    for (int sweep = 0; sweep < 6; ++sweep) {
        float off = A[0][1]*A[0][1] + A[0][2]*A[0][2] + A[1][2]*A[1][2];
        float dia = A[0][0]*A[0][0] + A[1][1]*A[1][1] + A[2][2]*A[2][2];
        if (off <= 1e-12f * (dia + 1e-30f)) break;
        for (int p = 0; p < 2; ++p) for (int q = p + 1; q < 3; ++q) {
            float apq = A[p][q];
            if (fabsf(apq) < 1e-30f) continue;
            float theta = (A[q][q] - A[p][p]) / (2.0f * apq);
            float t = ((theta >= 0.f) ? 1.f : -1.f) / (fabsf(theta) + sqrtf(theta*theta + 1.f));
            float cc = 1.f / sqrtf(t*t + 1.f);
            float ss = t * cc;
            float app = A[p][p], aqq = A[q][q];
            A[p][p] = app - t * apq;
            A[q][q] = aqq + t * apq;
            A[p][q] = 0.f; A[q][p] = 0.f;
            int r = 3 - p - q;
            float arp = A[r][p], arq = A[r][q];
            A[r][p] = cc*arp - ss*arq; A[p][r] = A[r][p];
            A[r][q] = ss*arp + cc*arq; A[q][r] = A[r][q];
            for (int i = 0; i < 3; ++i) {
                float vip = V[i][p], viq = V[i][q];
                V[i][p] = cc*vip - ss*viq;
                V[i][q] = ss*vip + cc*viq;
            }
        }
    }
}

__device__ void mat2quatf(const float R[3][3], float q[4]) {
    const float eps = 1e-12f;
    float tr = R[0][0] + R[1][1] + R[2][2];
    if (tr > 0.f) {
        float S = sqrtf(fmaxf(tr + 1.f, eps)) * 2.f;
        q[0] = (R[2][1]-R[1][2])/S; q[1] = (R[0][2]-R[2][0])/S;
        q[2] = (R[1][0]-R[0][1])/S; q[3] = 0.25f*S;
    } else if ((R[0][0] > R[1][1]) && (R[0][0] > R[2][2])) {
        float S = sqrtf(fmaxf(1.f + R[0][0] - R[1][1] - R[2][2], eps)) * 2.f;
        q[0] = 0.25f*S; q[1] = (R[0][1]+R[1][0])/S;
        q[2] = (R[0][2]+R[2][0])/S; q[3] = (R[2][1]-R[1][2])/S;
    } else if (R[1][1] > R[2][2]) {
        float S = sqrtf(fmaxf(1.f + R[1][1] - R[0][0] - R[2][2], eps)) * 2.f;
        q[0] = (R[0][1]+R[1][0])/S; q[1] = 0.25f*S;
        q[2] = (R[1][2]+R[2][1])/S; q[3] = (R[0][2]-R[2][0])/S;
    } else {
        float S = sqrtf(fmaxf(1.f + R[2][2] - R[0][0] - R[1][1], eps)) * 2.f;
        q[0] = (R[0][2]+R[2][0])/S; q[1] = (R[1][2]+R[2][1])/S;
        q[2] = 0.25f*S; q[3] = (R[1][0]-R[0][1])/S;
    }
}

__global__ __launch_bounds__(64) void finalize_kernel(
    const float* __restrict__ segacc, const int* __restrict__ counts,
    const int* __restrict__ starts, const float* __restrict__ pred_t,
    const float4* __restrict__ pred_q, const float4* __restrict__ gt_q,
    float* __restrict__ out, int E)
{
    int e = blockIdx.x * 64 + threadIdx.x;
    float v_trans = 0.f, v_rot = 0.f, v_grav = 0.f, v_leash = 0.f, v_scale = 0.f;
    if (e < E) {
        const float* A = segacc + (size_t)e * 32;
        int ci = counts[e];
        int start = starts[e];
        float c = (float)ci;
        float mu_p[3] = { A[0]/c, A[1]/c, A[2]/c };
        float mu_g[3] = { A[3]/c, A[4]/c, A[5]/c };
        float pp_c = A[6] - c*(mu_p[0]*mu_p[0]+mu_p[1]*mu_p[1]+mu_p[2]*mu_p[2]);
        float gg_c = A[7] - c*(mu_g[0]*mu_g[0]+mu_g[1]*mu_g[1]+mu_g[2]*mu_g[2]);
        float H[3][3];
        H[0][0]=A[8] -c*mu_p[0]*mu_g[0]; H[0][1]=A[9] -c*mu_p[0]*mu_g[1]; H[0][2]=A[10]-c*mu_p[0]*mu_g[2];
        H[1][0]=A[11]-c*mu_p[1]*mu_g[0]; H[1][1]=A[12]-c*mu_p[1]*mu_g[1]; H[1][2]=A[13]-c*mu_p[1]*mu_g[2];
        H[2][0]=A[14]-c*mu_p[2]*mu_g[0]; H[2][1]=A[15]-c*mu_p[2]*mu_g[1]; H[2][2]=A[16]-c*mu_p[2]*mu_g[2];
        float g_var = gg_c / (c - 1.0f);
        bool small_c = (ci < 4);
        bool deg = small_c || (g_var < 1e-4f);
        float trans, rot, scale = 0.f;
        if (deg) {
            float s28;
            if (small_c) {
                s28 = A[28];
            } else {
                // data-degenerate large segment (essentially never): re-stream
                float4 q0p = pred_q[start];
                float4 q0g = gt_q[start];
                float4 q0pi = make_float4(-q0p.x, -q0p.y, -q0p.z, q0p.w);
                float4 q0gi = make_float4(-q0g.x, -q0g.y, -q0g.z, q0g.w);
                float local = 0.f;
                for (int ii = 0; ii < ci; ++ii) {
                    float4 aa = qmul4(q0pi, pred_q[start + ii]);
                    float4 bb = qmul4(q0gi, gt_q[start + ii]);
                    float dd = aa.x*bb.x + aa.y*bb.y + aa.z*bb.z + aa.w*bb.w;
                    local += 1.f - dd*dd;
                }
                s28 = local;
            }
            float trH = H[0][0] + H[1][1] + H[2][2];
            trans = (pp_c - 2.f*trH + gg_c) / (c * 3.f);
            rot = s28 / c;
        } else {
            float B[3][3], V[3][3];
            for (int i = 0; i < 3; ++i)
                for (int j = 0; j < 3; ++j)
                    B[i][j] = H[0][i]*H[0][j] + H[1][i]*H[1][j] + H[2][i]*H[2][j];
            jacobi3f(B, V);
            float lam[3] = { B[0][0], B[1][1], B[2][2] };
            int idx[3] = {0, 1, 2};
            if (lam[idx[0]] < lam[idx[1]]) { int t = idx[0]; idx[0] = idx[1]; idx[1] = t; }
            if (lam[idx[0]] < lam[idx[2]]) { int t = idx[0]; idx[0] = idx[2]; idx[2] = t; }
            if (lam[idx[1]] < lam[idx[2]]) { int t = idx[1]; idx[1] = idx[2]; idx[2] = t; }
            float v1[3], v2[3], v3[3];
            for (int i = 0; i < 3; ++i) { v1[i] = V[i][idx[0]]; v2[i] = V[i][idx[1]]; v3[i] = V[i][idx[2]]; }
            float detV = v1[0]*(v2[1]*v3[2]-v2[2]*v3[1])
                       - v1[1]*(v2[0]*v3[2]-v2[2]*v3[0])
                       + v1[2]*(v2[0]*v3[1]-v2[1]*v3[0]);
            float sgnV = (detV < 0.f) ? -1.f : 1.f;
            float u1[3], u2[3], u3[3];
            for (int i = 0; i < 3; ++i) u1[i] = H[i][0]*v1[0] + H[i][1]*v1[1] + H[i][2]*v1[2];
            float n1 = fmaxf(sqrtf(u1[0]*u1[0]+u1[1]*u1[1]+u1[2]*u1[2]), 1e-30f);
            for (int i = 0; i < 3; ++i) u1[i] /= n1;
            for (int i = 0; i < 3; ++i) u2[i] = H[i][0]*v2[0] + H[i][1]*v2[1] + H[i][2]*v2[2];
            float d12 = u1[0]*u2[0]+u1[1]*u2[1]+u1[2]*u2[2];
            for (int i = 0; i < 3; ++i) u2[i] -= d12*u1[i];
            float n2 = fmaxf(sqrtf(u2[0]*u2[0]+u2[1]*u2[1]+u2[2]*u2[2]), 1e-30f);
            for (int i = 0; i < 3; ++i) u2[i] /= n2;
            u3[0] = u1[1]*u2[2] - u1[2]*u2[1];
            u3[1] = u1[2]*u2[0] - u1[0]*u2[2];
            u3[2] = u1[0]*u2[1] - u1[1]*u2[0];
            // R = v1 u1^T + v2 u2^T + sgnV*v3 u3^T (== ref V diag(1,1,sgn) U^T)
            float R[3][3];
            for (int i = 0; i < 3; ++i)
                for (int k = 0; k < 3; ++k)
                    R[i][k] = v1[i]*u1[k] + v2[i]*u2[k] + sgnV*v3[i]*u3[k];
            float nom = 0.f;
            for (int k = 0; k < 3; ++k)
                for (int j = 0; j < 3; ++j)
                    nom += R[k][j] * H[j][k];
            float denom = pp_c;
            float s = 1.f;
            if (denom > 1e-6f) {
                s = nom / fmaxf(denom, 1e-6f);
                s = fminf(fmaxf(s, 1e-3f), 1e3f);
            }
            trans = (s*s*denom - 2.f*s*nom + gg_c) / (c * 3.f);
            float ls = logf(fabsf(s) + 1e-6f);
            scale = ls * ls;
            float q[4];
            mat2quatf(R, q);
            float quad = q[0]*q[0]*A[17] + q[1]*q[1]*A[21] + q[2]*q[2]*A[24] + q[3]*q[3]*A[26]
                + 2.f*(q[0]*q[1]*A[18] + q[0]*q[2]*A[19] + q[0]*q[3]*A[20]
                     + q[1]*q[2]*A[22] + q[1]*q[3]*A[23] + q[2]*q[3]*A[25]);
            rot = (c - quad) / c;
        }
        float grav = A[27] / c;
        float tx = pred_t[3*start+0], ty = pred_t[3*start+1], tz = pred_t[3*start+2];
        float mag = sqrtf(tx*tx + ty*ty + tz*tz);
        float ml = fmaxf(mag - 15.f, 0.f);
        float Ed = (float)E;
        v_trans = trans / Ed;
        v_rot   = rot / Ed;
        v_grav  = grav / Ed;
        v_leash = (ml * ml) / Ed;
        v_scale = scale / Ed;
    }
    // wave-level reduce, 5 atomics per block (64 blocks -> 320 total)
    float vals[5] = { v_trans, v_rot, v_grav, v_leash, v_scale };
    #pragma unroll
    for (int k = 0; k < 5; ++k) {
        float v = wave_sum(vals[k]);
        if (threadIdx.x == 0) atomicAdd(out + k, v);
    }
}

extern "C" void kernel_launch(void* const* d_in, const int* in_sizes, int n_in,
                              void* d_out, int out_size, void* d_ws, size_t ws_size,
                              hipStream_t stream) {
    const float*  pred_t = (const float*)d_in[0];
    const float4* pred_q = (const float4*)d_in[1];
    const float*  gt_t   = (const float*)d_in[2];
    const float4* gt_q   = (const float4*)d_in[3];
    const int*    counts = (const int*)d_in[4];
    int E = in_sizes[4];

    int* starts = (int*)d_ws;
    size_t off = ((size_t)E * sizeof(int) + 255) & ~(size_t)255;
    float* segacc = (float*)((char*)d_ws + off);

    scan_kernel<<<1, 1024, 0, stream>>>(counts, starts, (float*)d_out, E);
    pass1_kernel<<<(E + 3) / 4, 256, 0, stream>>>(pred_t, pred_q, gt_t, gt_q,
                                                  counts, starts, segacc, E);
    finalize_kernel<<<(E + 63) / 64, 64, 0, stream>>>(segacc, counts, starts, pred_t,
                                                      pred_q, gt_q, (float*)d_out, E);
}